// Round 4
// baseline (537.424 us; speedup 1.0000x reference)
//
#include <hip/hip_runtime.h>
#include <hip/hip_bf16.h>
#include <cstdint>
#include <cstddef>

typedef unsigned short u16;
typedef unsigned int u32;
typedef __attribute__((ext_vector_type(8))) short short8;
typedef __attribute__((ext_vector_type(4))) float floatx4;

#define DD 1024
#define NE 8

// Tiled operand layout (Wgu, Wd, H): [128-row block][k-tile(32)][row(128)][pos(4)][8 bf16]
//   element (row s, k): block s>>7, kt = k>>5, r = s&127,
//   stored position p = ((k>>3)&3) ^ ((r>>1)&3)   (XOR baked; LDS image == swizzled image)
// Per-128-row block: 32 kt * 8192 B = 262144 B (131072 u16); per kt: 4096 u16.

// 16-byte async global->LDS copy (gfx950). LDS dest must be wave-uniform base + lane*16;
// global source address is per-lane (gather OK).
#define GLOAD_LDS16(G, L)                                               \
  __builtin_amdgcn_global_load_lds(                                     \
      (const __attribute__((address_space(1))) void*)(G),               \
      (__attribute__((address_space(3))) void*)(L), 16, 0, 0)

// LDS byte address (32-bit, ds-instruction space) of a __shared__ pointer.
#define LDSA(P) ((u32)(uintptr_t)(const __attribute__((address_space(3))) void*)(P))

// Inline-asm ds_read_b128: opaque to SIInsertWaitcnts' LDS-DMA hazard tracking,
// so in-flight global_load_lds stay in flight (counted vmcnt survives). Rule #18:
// consumer MFMAs are fenced by explicit lgkmcnt(0) + sched_barrier(0).
#define DSR(DST, ADDR, IMM)                                             \
  asm volatile("ds_read_b128 %0, %1 offset:" IMM : "=v"(DST) : "v"(ADDR))

__device__ __forceinline__ u16 f2bf(float f) {
  union { __hip_bfloat16 h; u16 u; } cv;
  cv.h = __float2bfloat16(f);
  return cv.u;
}

__device__ __forceinline__ float2 bf2f2(u32 u) {
  union { u32 v; float f; } lo, hi;
  lo.v = u << 16; hi.v = u & 0xffff0000u;
  float2 r; r.x = lo.f; r.y = hi.f; return r;
}

// ---------------- router: fp32 logits, top-2, softmax weights; emits x in bf16 ----------------
__global__ __launch_bounds__(256) void router_kernel(
    const float* __restrict__ x, const float* __restrict__ rw,
    const float* __restrict__ rb, int2* __restrict__ experts,
    float2* __restrict__ wts, u16* __restrict__ xbf, int T) {
  const int wave = threadIdx.x >> 6;
  const int lane = threadIdx.x & 63;
  const int t = blockIdx.x * 4 + wave;
  if (t >= T) return;
  const float* xr = x + (size_t)t * DD;
  float acc[NE] = {0.f, 0.f, 0.f, 0.f, 0.f, 0.f, 0.f, 0.f};
#pragma unroll
  for (int i = 0; i < 16; i++) {
    const int idx = lane + i * 64;
    const float xv = xr[idx];
    xbf[(size_t)t * DD + idx] = f2bf(xv);
    const float4* r4 = (const float4*)(rw + (size_t)idx * NE);
    float4 a = r4[0], b = r4[1];
    acc[0] += xv * a.x; acc[1] += xv * a.y; acc[2] += xv * a.z; acc[3] += xv * a.w;
    acc[4] += xv * b.x; acc[5] += xv * b.y; acc[6] += xv * b.z; acc[7] += xv * b.w;
  }
#pragma unroll
  for (int s = 1; s < 64; s <<= 1)
#pragma unroll
    for (int e = 0; e < NE; e++)
      acc[e] += __shfl_xor(acc[e], s);
  if (lane == 0) {
    float lg[NE];
#pragma unroll
    for (int e = 0; e < NE; e++) lg[e] = acc[e] + rb[e];
    float l0 = lg[0]; int i0 = 0;
#pragma unroll
    for (int e = 1; e < NE; e++) if (lg[e] > l0) { l0 = lg[e]; i0 = e; }
    float l1 = -3.4e38f; int i1 = 0;
#pragma unroll
    for (int e = 0; e < NE; e++) {
      if (e == i0) continue;
      if (lg[e] > l1) { l1 = lg[e]; i1 = e; }
    }
    const float w0 = 1.f / (1.f + expf(l1 - l0));
    experts[t] = make_int2(i0, i1);
    wts[t] = make_float2(w0, 1.f - w0);
  }
}

// ---------------- count tokens per expert ----------------
__global__ __launch_bounds__(256) void count_kernel(
    const int2* __restrict__ experts, int* __restrict__ counts, int T) {
  __shared__ int lc[NE];
  if (threadIdx.x < NE) lc[threadIdx.x] = 0;
  __syncthreads();
  const int t = blockIdx.x * 256 + threadIdx.x;
  if (t < T) {
    int2 e = experts[t];
    atomicAdd(&lc[e.x], 1);
    atomicAdd(&lc[e.y], 1);
  }
  __syncthreads();
  if (threadIdx.x < NE && lc[threadIdx.x] > 0)
    atomicAdd(&counts[threadIdx.x], lc[threadIdx.x]);
}

__global__ void offsets_kernel(const int* __restrict__ counts, int* __restrict__ offsets) {
  int s = 0;
  for (int e = 0; e < NE; e++) { offsets[e] = s; s += counts[e]; }
}

// ---------------- scatter: compact expert groups + inverse map (slots per token) ----------------
__global__ __launch_bounds__(256) void scatter_kernel(
    const int2* __restrict__ experts, const int* __restrict__ offsets,
    int* __restrict__ cursors, int* __restrict__ tok_id,
    int2* __restrict__ slots, int T) {
  __shared__ int lc[NE], lb[NE];
  if (threadIdx.x < NE) lc[threadIdx.x] = 0;
  __syncthreads();
  const int t = blockIdx.x * 256 + threadIdx.x;
  int2 e = make_int2(0, 0);
  int p0 = 0, p1 = 0;
  if (t < T) {
    e = experts[t];
    p0 = atomicAdd(&lc[e.x], 1);
    p1 = atomicAdd(&lc[e.y], 1);
  }
  __syncthreads();
  if (threadIdx.x < NE) lb[threadIdx.x] = atomicAdd(&cursors[threadIdx.x], lc[threadIdx.x]);
  __syncthreads();
  if (t < T) {
    const int s0 = offsets[e.x] + lb[e.x] + p0;
    const int s1 = offsets[e.y] + lb[e.y] + p1;
    tok_id[s0] = t;
    tok_id[s1] = t;
    slots[t] = make_int2(s0, s1);
  }
}

// ---------------- weight transpose + fp32->bf16 convert, tiled output ----------------
// Wgu expert-row nc = ((n>>3)<<4)|(mat<<3)|(n&7); tiled per 128-row block.
__global__ __launch_bounds__(256) void convert_kernel(
    const float* __restrict__ wg, const float* __restrict__ wu,
    const float* __restrict__ wd, u16* __restrict__ Wgu, u16* __restrict__ Wd) {
  const int z = blockIdx.z;        // mat*8 + e
  const int mat = z >> 3;
  const int e = z & 7;
  const float* src = (mat == 0 ? wg : (mat == 1 ? wu : wd)) + (size_t)e * DD * DD;
  __shared__ float tile[64][65];
  const int k0 = blockIdx.y * 64, n0 = blockIdx.x * 64;
  const int tx = threadIdx.x & 63, ty = threadIdx.x >> 6;
#pragma unroll
  for (int i = 0; i < 16; i++) {
    const int kk = i * 4 + ty;
    tile[kk][tx] = src[(size_t)(k0 + kk) * DD + n0 + tx];
  }
  __syncthreads();
  const int k = k0 + tx;
  const int kt = k >> 5, c = (k >> 3) & 3, j8 = k & 7;
#pragma unroll
  for (int i = 0; i < 16; i++) {
    const int nn = i * 4 + ty;
    const int n = n0 + nn;
    const u16 h = f2bf(tile[tx][nn]);   // = src[k0+tx][n]
    if (mat == 2) {
      const int r = n & 127, nb = n >> 7;
      const int pos = c ^ ((r >> 1) & 3);
      Wd[((size_t)(e * 8 + nb) * 32 + kt) * 4096 + r * 32 + pos * 8 + j8] = h;
    } else {
      const int nc = ((n >> 3) << 4) | (mat << 3) | (n & 7);
      const int r = nc & 127, nb = nc >> 7;
      const int pos = c ^ ((r >> 1) & 3);
      Wgu[((size_t)(e * 16 + nb) * 32 + kt) * 4096 + r * 32 + pos * 8 + j8] = h;
    }
  }
}

// ======================================================================
// 256x256-tile grouped GEMM engine, BK=32, 8 waves, 4-deep LDS ring with
// counted vmcnt (T3+T4), baked-swizzle tiled operands (T2), setprio (T5).
// B staging (and down's A staging) are contiguous 1 KB/instr streams,
// advance +8192 B per k-tile. gateup's A staging is the round-2-verified
// per-lane token gather (64-B row segments).
// Ring: prologue L0,L1,L2; iter kt: [stage L(kt+3)] [12 ds_read buf kt]
//   [lgkmcnt(0)] [32 MFMA] [vmcnt(8)] [barrier]; tail drains 4 -> 0.
// ======================================================================

#define STAGE(BUF, INCA)                                                \
  {                                                                     \
    GLOAD_LDS16(sA0, &As[(BUF) * 8192 + t * 8]);                        \
    GLOAD_LDS16(sA1, &As[(BUF) * 8192 + 4096 + t * 8]);                 \
    GLOAD_LDS16(sB0, &Bs[(BUF) * 8192 + t * 8]);                        \
    GLOAD_LDS16(sB1, &Bs[(BUF) * 8192 + 4096 + t * 8]);                 \
    sA0 += (INCA); sA1 += (INCA); sB0 += 4096; sB1 += 4096;             \
  }

#define COMPUTE(BUFOB, DO_STAGE, SBUF, INCA)                            \
  {                                                                     \
    if (DO_STAGE) { STAGE(SBUF, INCA); }                                \
    short8 a[8], b[4];                                                  \
    const u32 ab_ = asb + (u32)(BUFOB) + offAB;                         \
    const u32 bb_ = bsb + (u32)(BUFOB) + offBB;                         \
    DSR(a[0], ab_, "0");    DSR(a[1], ab_, "1024");                     \
    DSR(a[2], ab_, "2048"); DSR(a[3], ab_, "3072");                     \
    DSR(a[4], ab_, "4096"); DSR(a[5], ab_, "5120");                     \
    DSR(a[6], ab_, "6144"); DSR(a[7], ab_, "7168");                     \
    DSR(b[0], bb_, "0");    DSR(b[1], bb_, "1024");                     \
    DSR(b[2], bb_, "2048"); DSR(b[3], bb_, "3072");                     \
    asm volatile("s_waitcnt lgkmcnt(0)");                               \
    __builtin_amdgcn_sched_barrier(0);                                  \
    __builtin_amdgcn_s_setprio(1);                                      \
    _Pragma("unroll")                                                   \
    for (int i = 0; i < 8; i++)                                         \
      _Pragma("unroll")                                                 \
      for (int j = 0; j < 4; j++)                                       \
        acc[i][j] = __builtin_amdgcn_mfma_f32_16x16x32_bf16(            \
            a[i], b[j], acc[i][j], 0, 0, 0);                            \
    __builtin_amdgcn_s_setprio(0);                                      \
    __builtin_amdgcn_sched_barrier(0);                                  \
  }

#define SYNC(VM)                                                        \
  __builtin_amdgcn_sched_barrier(0);                                    \
  asm volatile("s_waitcnt vmcnt(" VM ")");                              \
  __builtin_amdgcn_s_barrier();                                         \
  __builtin_amdgcn_sched_barrier(0);

#define GEMM256_LOOP(INCA)                                              \
  STAGE(0, INCA); STAGE(1, INCA); STAGE(2, INCA);                       \
  SYNC("8");                                                            \
  _Pragma("unroll 1")                                                   \
  for (int kt = 0; kt < 29; ++kt) {                                     \
    COMPUTE((kt & 3) * 16384, 1, (kt + 3) & 3, INCA);                   \
    SYNC("8");                                                          \
  }                                                                     \
  COMPUTE(1 * 16384, 0, 0, INCA);                                       \
  SYNC("4");                                                            \
  COMPUTE(2 * 16384, 0, 0, INCA);                                       \
  SYNC("0");                                                            \
  COMPUTE(3 * 16384, 0, 0, INCA);

// ---------------- grouped GEMM 1: H = silu(x@Wg)*(x@Wu) ----------------
__global__ __launch_bounds__(512, 2) void gateup_kernel(
    const u16* __restrict__ xbf, const u16* __restrict__ Wgu,
    const int* __restrict__ tok_id, const int* __restrict__ offsets,
    const int* __restrict__ counts, u16* __restrict__ H) {
  const int e = blockIdx.z;
  const int cnt = counts[e];
  const int m0 = blockIdx.y * 256;
  if (m0 >= cnt) return;
  const int off = offsets[e];
  const int n0 = blockIdx.x * 256;

  __shared__ u16 As[4 * 8192];   // 4 bufs x [256 rows][32 k], 64 KB
  __shared__ u16 Bs[4 * 8192];   // 64 KB

  const int t = threadIdx.x;     // 0..511
  const int lane = t & 63;
  const int wave = t >> 6;       // 0..7
  const int wm = (wave >> 2) * 128;   // 2 M-waves
  const int wn = (wave & 3) * 64;     // 4 N-waves
  const int r16 = lane & 15;
  const int quad = lane >> 4;
  const int swz = quad ^ ((r16 >> 1) & 3);
  const u32 offAB = (u32)((wm + r16) * 64 + swz * 16);   // bytes
  const u32 offBB = (u32)((wn + r16) * 64 + swz * 16);
  const u32 asb = LDSA(&As[0]);
  const u32 bsb = LDSA(&Bs[0]);

  // A staging (round-2-verified): thread covers rows drow, drow+128; LDS pos = t&3
  // holds logical chunk c = pos ^ ((drow>>1)&3) of the token row.
  const int drow = t >> 2;
  const int pos = t & 3;
  const int c8 = (pos ^ ((drow >> 1) & 3)) * 8;
  int r0 = m0 + drow;       if (r0 > cnt - 1) r0 = cnt - 1;
  int r1 = m0 + drow + 128; if (r1 > cnt - 1) r1 = cnt - 1;
  const u16* sA0 = xbf + (size_t)tok_id[off + r0] * DD + c8;
  const u16* sA1 = xbf + (size_t)tok_id[off + r1] * DD + c8;
  // B staging (tiled, contiguous): LDS image == stored block image.
  const u16* sB0 = Wgu + (size_t)(e * 16 + (n0 >> 7)) * 131072 + t * 8;
  const u16* sB1 = Wgu + (size_t)(e * 16 + (n0 >> 7) + 1) * 131072 + t * 8;

  floatx4 acc[8][4];
#pragma unroll
  for (int i = 0; i < 8; i++)
#pragma unroll
    for (int j = 0; j < 4; j++)
      acc[i][j] = (floatx4){0.f, 0.f, 0.f, 0.f};

  GEMM256_LOOP(32);

  // epilogue: pair gate (bit3=0) with up (bit3=1) via shfl_xor 8, silu,
  // write bf16 H in tiled layout (absolute slot s; position = c ^ ((s>>1)&3)).
#pragma unroll
  for (int i = 0; i < 8; i++) {
    const int mb = m0 + wm + i * 16 + quad * 4;
#pragma unroll
    for (int j = 0; j < 4; j++) {
      const int nc = n0 + wn + j * 16 + r16;
      const int ng = ((nc >> 4) << 3) | (nc & 7);
      const int kt = ng >> 5, c = (ng >> 3) & 3, j8 = ng & 7;
#pragma unroll
      for (int r = 0; r < 4; r++) {
        const float v = acc[i][j][r];
        const float pv = __shfl_xor(v, 8);
        const float g = (lane & 8) ? pv : v;
        const float u = (lane & 8) ? v : pv;
        const float hv = g * u / (1.f + __expf(-g));
        const int m = mb + r;
        if (!(lane & 8) && m < cnt) {
          const int s = off + m;
          const int rr = s & 127;
          const int p2 = c ^ ((rr >> 1) & 3);
          H[(size_t)(s >> 7) * 131072 + kt * 4096 + rr * 32 + p2 * 8 + j8] = f2bf(hv);
        }
      }
    }
  }
}

// ---------------- grouped GEMM 2: Y[slot] = H[slot] @ Wd ----------------
__global__ __launch_bounds__(512, 2) void down_kernel(
    const u16* __restrict__ H, const u16* __restrict__ Wd,
    const int* __restrict__ counts, const int* __restrict__ offsets,
    u16* __restrict__ Y, int TK2) {
  const int e = blockIdx.z;
  const int cnt = counts[e];
  const int m0 = blockIdx.y * 256;
  if (m0 >= cnt) return;
  const int off = offsets[e];
  const int n0 = blockIdx.x * 256;

  __shared__ u16 As[4 * 8192];
  __shared__ u16 Bs[4 * 8192];

  const int t = threadIdx.x;
  const int lane = t & 63;
  const int wave = t >> 6;
  const int wm = (wave >> 2) * 128;
  const int wn = (wave & 3) * 64;
  const int r16 = lane & 15;
  const int quad = lane >> 4;
  const int swz = quad ^ ((r16 >> 1) & 3);
  const u32 offAB = (u32)((wm + r16) * 64 + swz * 16);
  const u32 offBB = (u32)((wn + r16) * 64 + swz * 16);
  const u32 asb = LDSA(&As[0]);
  const u32 bsb = LDSA(&Bs[0]);

  // A staging from tiled H: need logical chunk c = pos ^ ((drow>>1)&3) for slot s;
  // it is stored at position c ^ ((s>>1)&3). Correct for ANY expert offset.
  const int drow = t >> 2;
  const int pos = t & 3;
  const int c = pos ^ ((drow >> 1) & 3);
  int s0 = off + m0 + drow;        if (s0 > TK2 - 1) s0 = TK2 - 1;
  int s1 = off + m0 + drow + 128;  if (s1 > TK2 - 1) s1 = TK2 - 1;
  const u16* sA0 = H + (size_t)(s0 >> 7) * 131072 + (s0 & 127) * 32 + (c ^ ((s0 >> 1) & 3)) * 8;
  const u16* sA1 = H + (size_t)(s1 >> 7) * 131072 + (s1 & 127) * 32 + (c ^ ((s1 >> 1) & 3)) * 8;
  const u16* sB0 = Wd + (size_t)(e * 8 + (n0 >> 7)) * 131072 + t * 8;
  const u16* sB1 = Wd + (size_t)(e * 8 + (n0 >> 7) + 1) * 131072 + t * 8;

  floatx4 acc[8][4];
#pragma unroll
  for (int i = 0; i < 8; i++)
#pragma unroll
    for (int j = 0; j < 4; j++)
      acc[i][j] = (floatx4){0.f, 0.f, 0.f, 0.f};

  GEMM256_LOOP(4096);

#pragma unroll
  for (int i = 0; i < 8; i++) {
    const int mb = m0 + wm + i * 16 + quad * 4;
#pragma unroll
    for (int r = 0; r < 4; r++) {
      const int m = mb + r;
      if (m < cnt) {
        u16* yrow = Y + (size_t)(off + m) * DD + n0 + wn + r16;
#pragma unroll
        for (int j = 0; j < 4; j++)
          yrow[j * 16] = f2bf(acc[i][j][r]);
      }
    }
  }
}

#undef STAGE
#undef COMPUTE
#undef SYNC

// ---------------- combine: out[t] = w0*Y[s0] + w1*Y[s1] ----------------
__global__ __launch_bounds__(256) void combine_kernel(
    const u16* __restrict__ Y, const int2* __restrict__ slots,
    const float2* __restrict__ wts, float* __restrict__ out, int T) {
  const int wave = threadIdx.x >> 6;
  const int lane = threadIdx.x & 63;
  const int t = blockIdx.x * 4 + wave;
  if (t >= T) return;
  const int2 s = slots[t];
  const float2 w = wts[t];
  const uint4* y0 = (const uint4*)(Y + (size_t)s.x * DD);
  const uint4* y1 = (const uint4*)(Y + (size_t)s.y * DD);
  float4* o = (float4*)(out + (size_t)t * DD);
#pragma unroll
  for (int c = 0; c < 2; c++) {
    const int idx = lane + c * 64;          // 128 uint4 per row (8 bf16 each)
    const uint4 a = y0[idx];
    const uint4 b = y1[idx];
    const u32 au[4] = {a.x, a.y, a.z, a.w};
    const u32 bu[4] = {b.x, b.y, b.z, b.w};
    float4 r[2];
#pragma unroll
    for (int q = 0; q < 4; q++) {
      const float2 fa = bf2f2(au[q]);
      const float2 fb = bf2f2(bu[q]);
      ((float*)r)[q * 2]     = w.x * fa.x + w.y * fb.x;
      ((float*)r)[q * 2 + 1] = w.x * fa.y + w.y * fb.y;
    }
    o[idx * 2]     = r[0];
    o[idx * 2 + 1] = r[1];
  }
}

extern "C" void kernel_launch(void* const* d_in, const int* in_sizes, int n_in,
                              void* d_out, int out_size, void* d_ws, size_t ws_size,
                              hipStream_t stream) {
  const float* x  = (const float*)d_in[0];
  const float* rw = (const float*)d_in[1];
  const float* rb = (const float*)d_in[2];
  const float* wg = (const float*)d_in[3];
  const float* wu = (const float*)d_in[4];
  const float* wd = (const float*)d_in[5];
  float* out = (float*)d_out;
  const int T = in_sizes[0] / DD;       // 16384
  const int TK2 = 2 * T;

  // workspace carve (== round-2's 144.9 MB, which passed the guard).
  // Y (64MB) aliases [Wgu(32MB) xbf(32MB)], both dead after gateup.
  char* p = (char*)d_ws;
  int* ctrl = (int*)p; p += 256;        // [0..7]=counts [8..15]=cursors [16..23]=offsets
  int2* experts = (int2*)p;  p += (size_t)T * 8;
  float2* wtsp  = (float2*)p; p += (size_t)T * 8;
  int* tok_id   = (int*)p;   p += (size_t)TK2 * 4;
  int2* slots   = (int2*)p;  p += (size_t)T * 8;
  u16* Wd       = (u16*)p;   p += (size_t)NE * DD * DD * 2;   // 16 MB (tiled)
  u16* H        = (u16*)p;   p += (size_t)TK2 * DD * 2;       // 64 MB (tiled)
  u16* Wgu      = (u16*)p;   // 32 MB (tiled)
  u16* xbf      = (u16*)(p + (size_t)NE * 2048 * DD * 2);  // 32 MB (row-major)
  u16* Y        = (u16*)p;   // 64 MB, aliases Wgu+xbf
  p += (size_t)TK2 * DD * 2;
  if ((size_t)(p - (char*)d_ws) > ws_size) return;  // insufficient scratch -> visible failure

  hipMemsetAsync(ctrl, 0, 256, stream);

  router_kernel<<<T / 4, 256, 0, stream>>>(x, rw, rb, experts, wtsp, xbf, T);
  count_kernel<<<T / 256, 256, 0, stream>>>(experts, ctrl, T);
  offsets_kernel<<<1, 1, 0, stream>>>(ctrl, ctrl + 16);
  scatter_kernel<<<T / 256, 256, 0, stream>>>(experts, ctrl + 16, ctrl + 8, tok_id, slots, T);
  convert_kernel<<<dim3(16, 16, 24), 256, 0, stream>>>(wg, wu, wd, Wgu, Wd);
  gateup_kernel<<<dim3(8, (T + 255) / 256, NE), 512, 0, stream>>>(
      xbf, Wgu, tok_id, ctrl + 16, ctrl, H);
  down_kernel<<<dim3(4, (T + 255) / 256, NE), 512, 0, stream>>>(
      H, Wd, ctrl, ctrl + 16, Y, TK2);
  combine_kernel<<<T / 4, 256, 0, stream>>>(Y, slots, wtsp, out, T);
}

// Round 5
// 529.232 us; speedup vs baseline: 1.0155x; 1.0155x over previous
//
#include <hip/hip_runtime.h>
#include <hip/hip_bf16.h>
#include <cstdint>
#include <cstddef>

typedef unsigned short u16;
typedef unsigned int u32;
typedef __attribute__((ext_vector_type(8))) short short8;
typedef __attribute__((ext_vector_type(4))) float floatx4;

#define DD 1024
#define NE 8

// 16-byte async global->LDS copy (gfx950). LDS dest must be wave-uniform base + lane*16;
// global source address is per-lane (gather OK).
#define GLOAD_LDS16(G, L)                                               \
  __builtin_amdgcn_global_load_lds(                                     \
      (const __attribute__((address_space(1))) void*)(G),               \
      (__attribute__((address_space(3))) void*)(L), 16, 0, 0)

// LDS byte address (32-bit, ds-instruction space) of a __shared__ pointer.
#define LDSA(P) ((u32)(uintptr_t)(const __attribute__((address_space(3))) void*)(P))

// Inline-asm ds_read_b128: opaque to SIInsertWaitcnts' LDS-DMA hazard tracking,
// so the in-flight global_load_lds for the NEXT buffer stay in flight while we
// read the current buffer. Rule #18: consumers fenced by lgkmcnt(0)+sched_barrier.
#define DSR(DST, ADDR, IMM)                                             \
  asm volatile("ds_read_b128 %0, %1 offset:" IMM : "=v"(DST) : "v"(ADDR))

__device__ __forceinline__ u16 f2bf(float f) {
  union { __hip_bfloat16 h; u16 u; } cv;
  cv.h = __float2bfloat16(f);
  return cv.u;
}

__device__ __forceinline__ float2 bf2f2(u32 u) {
  union { u32 v; float f; } lo, hi;
  lo.v = u << 16; hi.v = u & 0xffff0000u;
  float2 r; r.x = lo.f; r.y = hi.f; return r;
}

// ---------------- router: fp32 logits, top-2, softmax weights; emits x in bf16 ----------------
__global__ __launch_bounds__(256) void router_kernel(
    const float* __restrict__ x, const float* __restrict__ rw,
    const float* __restrict__ rb, int2* __restrict__ experts,
    float2* __restrict__ wts, u16* __restrict__ xbf, int T) {
  const int wave = threadIdx.x >> 6;
  const int lane = threadIdx.x & 63;
  const int t = blockIdx.x * 4 + wave;
  if (t >= T) return;
  const float* xr = x + (size_t)t * DD;
  float acc[NE] = {0.f, 0.f, 0.f, 0.f, 0.f, 0.f, 0.f, 0.f};
#pragma unroll
  for (int i = 0; i < 16; i++) {
    const int idx = lane + i * 64;
    const float xv = xr[idx];
    xbf[(size_t)t * DD + idx] = f2bf(xv);
    const float4* r4 = (const float4*)(rw + (size_t)idx * NE);
    float4 a = r4[0], b = r4[1];
    acc[0] += xv * a.x; acc[1] += xv * a.y; acc[2] += xv * a.z; acc[3] += xv * a.w;
    acc[4] += xv * b.x; acc[5] += xv * b.y; acc[6] += xv * b.z; acc[7] += xv * b.w;
  }
#pragma unroll
  for (int s = 1; s < 64; s <<= 1)
#pragma unroll
    for (int e = 0; e < NE; e++)
      acc[e] += __shfl_xor(acc[e], s);
  if (lane == 0) {
    float lg[NE];
#pragma unroll
    for (int e = 0; e < NE; e++) lg[e] = acc[e] + rb[e];
    float l0 = lg[0]; int i0 = 0;
#pragma unroll
    for (int e = 1; e < NE; e++) if (lg[e] > l0) { l0 = lg[e]; i0 = e; }
    float l1 = -3.4e38f; int i1 = 0;
#pragma unroll
    for (int e = 0; e < NE; e++) {
      if (e == i0) continue;
      if (lg[e] > l1) { l1 = lg[e]; i1 = e; }
    }
    const float w0 = 1.f / (1.f + expf(l1 - l0));
    experts[t] = make_int2(i0, i1);
    wts[t] = make_float2(w0, 1.f - w0);
  }
}

// ---------------- count tokens per expert ----------------
__global__ __launch_bounds__(256) void count_kernel(
    const int2* __restrict__ experts, int* __restrict__ counts, int T) {
  __shared__ int lc[NE];
  if (threadIdx.x < NE) lc[threadIdx.x] = 0;
  __syncthreads();
  const int t = blockIdx.x * 256 + threadIdx.x;
  if (t < T) {
    int2 e = experts[t];
    atomicAdd(&lc[e.x], 1);
    atomicAdd(&lc[e.y], 1);
  }
  __syncthreads();
  if (threadIdx.x < NE && lc[threadIdx.x] > 0)
    atomicAdd(&counts[threadIdx.x], lc[threadIdx.x]);
}

__global__ void offsets_kernel(const int* __restrict__ counts, int* __restrict__ offsets) {
  int s = 0;
  for (int e = 0; e < NE; e++) { offsets[e] = s; s += counts[e]; }
}

// ---------------- scatter: compact expert groups + inverse map (slots per token) ----------------
__global__ __launch_bounds__(256) void scatter_kernel(
    const int2* __restrict__ experts, const int* __restrict__ offsets,
    int* __restrict__ cursors, int* __restrict__ tok_id,
    int2* __restrict__ slots, int T) {
  __shared__ int lc[NE], lb[NE];
  if (threadIdx.x < NE) lc[threadIdx.x] = 0;
  __syncthreads();
  const int t = blockIdx.x * 256 + threadIdx.x;
  int2 e = make_int2(0, 0);
  int p0 = 0, p1 = 0;
  if (t < T) {
    e = experts[t];
    p0 = atomicAdd(&lc[e.x], 1);
    p1 = atomicAdd(&lc[e.y], 1);
  }
  __syncthreads();
  if (threadIdx.x < NE) lb[threadIdx.x] = atomicAdd(&cursors[threadIdx.x], lc[threadIdx.x]);
  __syncthreads();
  if (t < T) {
    const int s0 = offsets[e.x] + lb[e.x] + p0;
    const int s1 = offsets[e.y] + lb[e.y] + p1;
    tok_id[s0] = t;
    tok_id[s1] = t;
    slots[t] = make_int2(s0, s1);
  }
}

// ---------------- weight transpose + fp32->bf16 convert ----------------
// Wgu: [e][nc][k], nc = ((n>>3)<<4) | (which<<3) | (n&7); Wd: [e][n][k]
__global__ __launch_bounds__(256) void convert_kernel(
    const float* __restrict__ wg, const float* __restrict__ wu,
    const float* __restrict__ wd, u16* __restrict__ Wgu, u16* __restrict__ Wd) {
  const int z = blockIdx.z;        // mat*8 + e
  const int mat = z >> 3;
  const int e = z & 7;
  const float* src = (mat == 0 ? wg : (mat == 1 ? wu : wd)) + (size_t)e * DD * DD;
  __shared__ float tile[64][65];
  const int k0 = blockIdx.y * 64, n0 = blockIdx.x * 64;
  const int tx = threadIdx.x & 63, ty = threadIdx.x >> 6;
#pragma unroll
  for (int i = 0; i < 16; i++) {
    const int kk = i * 4 + ty;
    tile[kk][tx] = src[(size_t)(k0 + kk) * DD + n0 + tx];
  }
  __syncthreads();
#pragma unroll
  for (int i = 0; i < 16; i++) {
    const int nn = i * 4 + ty;
    const int n = n0 + nn;
    const u16 h = f2bf(tile[tx][nn]);   // = src[k0+tx][n]
    if (mat == 2) {
      Wd[((size_t)e * DD + n) * DD + k0 + tx] = h;
    } else {
      const int nc = ((n >> 3) << 4) | (mat << 3) | (n & 7);
      Wgu[((size_t)e * 2048 + nc) * DD + k0 + tx] = h;
    }
  }
}

// ======================================================================
// 128x128-tile grouped GEMM engine (round-0 geometry/data layout, verified),
// K-loop rebuilt as the catalog's minimum-2-phase recipe (T3-min):
//   prologue: STAGE(buf0, k=0); vmcnt(0); barrier
//   iter kk:  STAGE(buf[cur^1], k+64)   <- issued BEFORE compute
//             ds_read buf[cur] (asm DSR), lgkmcnt(0), 32 MFMA (setprio)
//             vmcnt(0); barrier; cur ^= 1   <- ONE barrier per K-step
//   epilogue: compute buf[cur] (no prefetch)
// Stage latency hides under the MFMA cluster + 2-blocks/CU TLP (64 KB LDS).
// ======================================================================

#define STAGE(BUF, KOFF)                                                \
  {                                                                     \
    _Pragma("unroll")                                                   \
    for (int i = 0; i < 4; i++) {                                       \
      GLOAD_LDS16(srcA[i] + (KOFF), &As[(BUF) * 8192 + t * 8 + i * 2048]); \
      GLOAD_LDS16(srcB[i] + (KOFF), &Bs[(BUF) * 8192 + t * 8 + i * 2048]); \
    }                                                                   \
  }

#define COMPUTE(BUF)                                                    \
  {                                                                     \
    _Pragma("unroll")                                                   \
    for (int s = 0; s < 2; s++) {                                       \
      short8 a[4], b[4];                                                \
      const u32 ab_ = asb + (u32)(BUF) * 16384u + offA + cks[s];        \
      const u32 bb_ = bsb + (u32)(BUF) * 16384u + offB + cks[s];        \
      DSR(a[0], ab_, "0");    DSR(a[1], ab_, "2048");                   \
      DSR(a[2], ab_, "4096"); DSR(a[3], ab_, "6144");                   \
      DSR(b[0], bb_, "0");    DSR(b[1], bb_, "2048");                   \
      DSR(b[2], bb_, "4096"); DSR(b[3], bb_, "6144");                   \
      asm volatile("s_waitcnt lgkmcnt(0)");                             \
      __builtin_amdgcn_sched_barrier(0);                                \
      __builtin_amdgcn_s_setprio(1);                                    \
      _Pragma("unroll")                                                 \
      for (int i = 0; i < 4; i++)                                       \
        _Pragma("unroll")                                               \
        for (int j = 0; j < 4; j++)                                     \
          acc[i][j] = __builtin_amdgcn_mfma_f32_16x16x32_bf16(          \
              a[i], b[j], acc[i][j], 0, 0, 0);                          \
      __builtin_amdgcn_s_setprio(0);                                    \
      __builtin_amdgcn_sched_barrier(0);                                \
    }                                                                   \
  }

#define SYNC0()                                                         \
  __builtin_amdgcn_sched_barrier(0);                                    \
  asm volatile("s_waitcnt vmcnt(0)");                                   \
  __builtin_amdgcn_s_barrier();                                         \
  __builtin_amdgcn_sched_barrier(0);

#define GEMM128_LOOP()                                                  \
  STAGE(0, 0);                                                          \
  SYNC0();                                                              \
  int cur = 0;                                                          \
  _Pragma("unroll 1")                                                   \
  for (int kk = 0; kk < 15; ++kk) {                                     \
    STAGE(cur ^ 1, (kk + 1) * 64);                                      \
    COMPUTE(cur);                                                       \
    SYNC0();                                                            \
    cur ^= 1;                                                           \
  }                                                                     \
  COMPUTE(cur);

// ---------------- grouped GEMM 1: H = silu(x@Wg)*(x@Wu) ----------------
__global__ __launch_bounds__(256, 2) void gateup_kernel(
    const u16* __restrict__ xbf, const u16* __restrict__ Wgu,
    const int* __restrict__ tok_id, const int* __restrict__ offsets,
    const int* __restrict__ counts, u16* __restrict__ H) {
  const int e = blockIdx.z;
  const int cnt = counts[e];
  const int m0 = blockIdx.y * 128;
  if (m0 >= cnt) return;
  const int off = offsets[e];
  const int n0 = blockIdx.x * 128;

  __shared__ u16 As[2 * 8192];   // 2 bufs x [128 rows][64 k] = 32 KB
  __shared__ u16 Bs[2 * 8192];   // 32 KB

  const int t = threadIdx.x;
  const int lane = t & 63;
  const int wave = t >> 6;
  const int wm = (wave >> 1) * 64;
  const int wn = (wave & 1) * 64;
  const int r16 = lane & 15;
  const int quad = lane >> 4;
  const u32 offA = (u32)((wm + r16) * 128);     // byte offset of row base
  const u32 offB = (u32)((wn + r16) * 128);
  u32 cks[2];
  cks[0] = (u32)(((quad) ^ (r16 & 7)) * 16);
  cks[1] = (u32)(((4 + quad) ^ (r16 & 7)) * 16);
  const u32 asb = LDSA(&As[0]);
  const u32 bsb = LDSA(&Bs[0]);

  // DMA mapping (round-0 verified): issue i covers rows i*32 + (t>>3); lane supplies
  // chunk position t&7, whose LOGICAL k-chunk is (t&7) ^ (row&7) (XOR swizzle).
  const int drow = t >> 3;
  const int dpos = t & 7;
  const u16* srcA[4];
  const u16* srcB[4];
  const u16* bbase = Wgu + ((size_t)e * 2048 + n0) * DD;
#pragma unroll
  for (int i = 0; i < 4; i++) {
    const int row = drow + i * 32;
    int r = m0 + row; if (r > cnt - 1) r = cnt - 1;
    const int tok = tok_id[off + r];
    const int ka = (dpos ^ (row & 7)) * 8;
    srcA[i] = xbf + (size_t)tok * DD + ka;
    srcB[i] = bbase + (size_t)row * DD + ka;
  }

  floatx4 acc[4][4];
#pragma unroll
  for (int i = 0; i < 4; i++)
#pragma unroll
    for (int j = 0; j < 4; j++)
      acc[i][j] = (floatx4){0.f, 0.f, 0.f, 0.f};

  GEMM128_LOOP();

  // epilogue: pair gate (bit3=0) with up (bit3=1) via shfl_xor 8, silu, write bf16 H
#pragma unroll
  for (int i = 0; i < 4; i++) {
    const int mb = m0 + wm + i * 16 + quad * 4;
#pragma unroll
    for (int j = 0; j < 4; j++) {
      const int nc = n0 + wn + j * 16 + r16;
      const int ng = ((nc >> 4) << 3) | (nc & 7);
#pragma unroll
      for (int r = 0; r < 4; r++) {
        const float v = acc[i][j][r];
        const float pv = __shfl_xor(v, 8);
        const float g = (lane & 8) ? pv : v;
        const float u = (lane & 8) ? v : pv;
        const float hv = g * u / (1.f + __expf(-g));
        const int m = mb + r;
        if (!(lane & 8) && m < cnt)
          H[(size_t)(off + m) * DD + ng] = f2bf(hv);
      }
    }
  }
}

// ---------------- grouped GEMM 2: Y[slot] = H[slot] @ Wd  (bf16 stores, no atomics) ----------------
__global__ __launch_bounds__(256, 2) void down_kernel(
    const u16* __restrict__ H, const u16* __restrict__ Wd,
    const int* __restrict__ counts, const int* __restrict__ offsets,
    u16* __restrict__ Y, int TK2) {
  const int e = blockIdx.z;
  const int cnt = counts[e];
  const int m0 = blockIdx.y * 128;
  if (m0 >= cnt) return;
  const int off = offsets[e];
  const int n0 = blockIdx.x * 128;

  __shared__ u16 As[2 * 8192];
  __shared__ u16 Bs[2 * 8192];

  const int t = threadIdx.x;
  const int lane = t & 63;
  const int wave = t >> 6;
  const int wm = (wave >> 1) * 64;
  const int wn = (wave & 1) * 64;
  const int r16 = lane & 15;
  const int quad = lane >> 4;
  const u32 offA = (u32)((wm + r16) * 128);
  const u32 offB = (u32)((wn + r16) * 128);
  u32 cks[2];
  cks[0] = (u32)(((quad) ^ (r16 & 7)) * 16);
  cks[1] = (u32)(((4 + quad) ^ (r16 & 7)) * 16);
  const u32 asb = LDSA(&As[0]);
  const u32 bsb = LDSA(&Bs[0]);

  const int drow = t >> 3;
  const int dpos = t & 7;
  const u16* srcA[4];
  const u16* srcB[4];
  const u16* bbase = Wd + ((size_t)e * DD + n0) * DD;
#pragma unroll
  for (int i = 0; i < 4; i++) {
    const int row = drow + i * 32;
    int r = off + m0 + row; if (r > TK2 - 1) r = TK2 - 1;
    const int ka = (dpos ^ (row & 7)) * 8;
    srcA[i] = H + (size_t)r * DD + ka;
    srcB[i] = bbase + (size_t)row * DD + ka;
  }

  floatx4 acc[4][4];
#pragma unroll
  for (int i = 0; i < 4; i++)
#pragma unroll
    for (int j = 0; j < 4; j++)
      acc[i][j] = (floatx4){0.f, 0.f, 0.f, 0.f};

  GEMM128_LOOP();

#pragma unroll
  for (int i = 0; i < 4; i++) {
    const int mb = m0 + wm + i * 16 + quad * 4;
#pragma unroll
    for (int r = 0; r < 4; r++) {
      const int m = mb + r;
      if (m < cnt) {
        u16* yrow = Y + (size_t)(off + m) * DD + n0 + wn + r16;
#pragma unroll
        for (int j = 0; j < 4; j++)
          yrow[j * 16] = f2bf(acc[i][j][r]);
      }
    }
  }
}

#undef STAGE
#undef COMPUTE
#undef SYNC0

// ---------------- combine: out[t] = w0*Y[s0] + w1*Y[s1] ----------------
__global__ __launch_bounds__(256) void combine_kernel(
    const u16* __restrict__ Y, const int2* __restrict__ slots,
    const float2* __restrict__ wts, float* __restrict__ out, int T) {
  const int wave = threadIdx.x >> 6;
  const int lane = threadIdx.x & 63;
  const int t = blockIdx.x * 4 + wave;
  if (t >= T) return;
  const int2 s = slots[t];
  const float2 w = wts[t];
  const uint4* y0 = (const uint4*)(Y + (size_t)s.x * DD);
  const uint4* y1 = (const uint4*)(Y + (size_t)s.y * DD);
  float4* o = (float4*)(out + (size_t)t * DD);
#pragma unroll
  for (int c = 0; c < 2; c++) {
    const int idx = lane + c * 64;          // 128 uint4 per row (8 bf16 each)
    const uint4 a = y0[idx];
    const uint4 b = y1[idx];
    const u32 au[4] = {a.x, a.y, a.z, a.w};
    const u32 bu[4] = {b.x, b.y, b.z, b.w};
    float4 r[2];
#pragma unroll
    for (int q = 0; q < 4; q++) {
      const float2 fa = bf2f2(au[q]);
      const float2 fb = bf2f2(bu[q]);
      ((float*)r)[q * 2]     = w.x * fa.x + w.y * fb.x;
      ((float*)r)[q * 2 + 1] = w.x * fa.y + w.y * fb.y;
    }
    o[idx * 2]     = r[0];
    o[idx * 2 + 1] = r[1];
  }
}

extern "C" void kernel_launch(void* const* d_in, const int* in_sizes, int n_in,
                              void* d_out, int out_size, void* d_ws, size_t ws_size,
                              hipStream_t stream) {
  const float* x  = (const float*)d_in[0];
  const float* rw = (const float*)d_in[1];
  const float* rb = (const float*)d_in[2];
  const float* wg = (const float*)d_in[3];
  const float* wu = (const float*)d_in[4];
  const float* wd = (const float*)d_in[5];
  float* out = (float*)d_out;
  const int T = in_sizes[0] / DD;       // 16384
  const int TK2 = 2 * T;

  // workspace carve. Y (64MB) aliases [Wgu(32MB) xbf(32MB)], which are dead after gateup.
  char* p = (char*)d_ws;
  int* ctrl = (int*)p; p += 256;        // [0..7]=counts [8..15]=cursors [16..23]=offsets
  int2* experts = (int2*)p;  p += (size_t)T * 8;
  float2* wtsp  = (float2*)p; p += (size_t)T * 8;
  int* tok_id   = (int*)p;   p += (size_t)TK2 * 4;
  int2* slots   = (int2*)p;  p += (size_t)T * 8;
  u16* Wd       = (u16*)p;   p += (size_t)NE * DD * DD * 2;
  u16* H        = (u16*)p;   p += (size_t)TK2 * DD * 2;
  u16* Wgu      = (u16*)p;   // 32 MB
  u16* xbf      = (u16*)(p + (size_t)NE * 2048 * DD * 2);  // 32 MB
  u16* Y        = (u16*)p;   // 64 MB, aliases Wgu+xbf
  p += (size_t)TK2 * DD * 2;
  if ((size_t)(p - (char*)d_ws) > ws_size) return;  // insufficient scratch -> visible failure

  hipMemsetAsync(ctrl, 0, 256, stream);

  router_kernel<<<T / 4, 256, 0, stream>>>(x, rw, rb, experts, wtsp, xbf, T);
  count_kernel<<<T / 256, 256, 0, stream>>>(experts, ctrl, T);
  offsets_kernel<<<1, 1, 0, stream>>>(ctrl, ctrl + 16);
  scatter_kernel<<<T / 256, 256, 0, stream>>>(experts, ctrl + 16, ctrl + 8, tok_id, slots, T);
  convert_kernel<<<dim3(16, 16, 24), 256, 0, stream>>>(wg, wu, wd, Wgu, Wd);
  gateup_kernel<<<dim3(16, (T + 127) / 128, NE), 256, 0, stream>>>(
      xbf, Wgu, tok_id, ctrl + 16, ctrl, H);
  down_kernel<<<dim3(8, (T + 127) / 128, NE), 256, 0, stream>>>(
      H, Wd, ctrl, ctrl + 16, Y, TK2);
  combine_kernel<<<T / 4, 256, 0, stream>>>(Y, slots, wtsp, out, T);
}

// Round 6
// 516.716 us; speedup vs baseline: 1.0401x; 1.0242x over previous
//
#include <hip/hip_runtime.h>
#include <hip/hip_bf16.h>
#include <cstdint>
#include <cstddef>

typedef unsigned short u16;
typedef unsigned int u32;
typedef __attribute__((ext_vector_type(8))) short short8;
typedef __attribute__((ext_vector_type(4))) float floatx4;

#define DD 1024
#define NE 8

// 16-byte async global->LDS copy (gfx950). LDS dest must be wave-uniform base + lane*16;
// global source address is per-lane (gather OK).
#define GLOAD_LDS16(G, L)                                               \
  __builtin_amdgcn_global_load_lds(                                     \
      (const __attribute__((address_space(1))) void*)(G),               \
      (__attribute__((address_space(3))) void*)(L), 16, 0, 0)

// LDS byte address (32-bit, ds-instruction space) of a __shared__ pointer.
#define LDSA(P) ((u32)(uintptr_t)(const __attribute__((address_space(3))) void*)(P))

// Inline-asm ds_read_b128: opaque to SIInsertWaitcnts' LDS-DMA hazard tracking,
// so the in-flight global_load_lds for the NEXT buffer stay in flight while we
// read the current buffer. Rule #18: consumers fenced by lgkmcnt(0)+sched_barrier.
#define DSR(DST, ADDR, IMM)                                             \
  asm volatile("ds_read_b128 %0, %1 offset:" IMM : "=v"(DST) : "v"(ADDR))

__device__ __forceinline__ u16 f2bf(float f) {
  union { __hip_bfloat16 h; u16 u; } cv;
  cv.h = __float2bfloat16(f);
  return cv.u;
}

__device__ __forceinline__ float2 bf2f2(u32 u) {
  union { u32 v; float f; } lo, hi;
  lo.v = u << 16; hi.v = u & 0xffff0000u;
  float2 r; r.x = lo.f; r.y = hi.f; return r;
}

// ---------------- router: fp32 logits, top-2, softmax weights; emits x in bf16 ----------------
__global__ __launch_bounds__(256) void router_kernel(
    const float* __restrict__ x, const float* __restrict__ rw,
    const float* __restrict__ rb, int2* __restrict__ experts,
    float2* __restrict__ wts, u16* __restrict__ xbf, int T) {
  const int wave = threadIdx.x >> 6;
  const int lane = threadIdx.x & 63;
  const int t = blockIdx.x * 4 + wave;
  if (t >= T) return;
  const float* xr = x + (size_t)t * DD;
  float acc[NE] = {0.f, 0.f, 0.f, 0.f, 0.f, 0.f, 0.f, 0.f};
#pragma unroll
  for (int i = 0; i < 16; i++) {
    const int idx = lane + i * 64;
    const float xv = xr[idx];
    xbf[(size_t)t * DD + idx] = f2bf(xv);
    const float4* r4 = (const float4*)(rw + (size_t)idx * NE);
    float4 a = r4[0], b = r4[1];
    acc[0] += xv * a.x; acc[1] += xv * a.y; acc[2] += xv * a.z; acc[3] += xv * a.w;
    acc[4] += xv * b.x; acc[5] += xv * b.y; acc[6] += xv * b.z; acc[7] += xv * b.w;
  }
#pragma unroll
  for (int s = 1; s < 64; s <<= 1)
#pragma unroll
    for (int e = 0; e < NE; e++)
      acc[e] += __shfl_xor(acc[e], s);
  if (lane == 0) {
    float lg[NE];
#pragma unroll
    for (int e = 0; e < NE; e++) lg[e] = acc[e] + rb[e];
    float l0 = lg[0]; int i0 = 0;
#pragma unroll
    for (int e = 1; e < NE; e++) if (lg[e] > l0) { l0 = lg[e]; i0 = e; }
    float l1 = -3.4e38f; int i1 = 0;
#pragma unroll
    for (int e = 0; e < NE; e++) {
      if (e == i0) continue;
      if (lg[e] > l1) { l1 = lg[e]; i1 = e; }
    }
    const float w0 = 1.f / (1.f + expf(l1 - l0));
    experts[t] = make_int2(i0, i1);
    wts[t] = make_float2(w0, 1.f - w0);
  }
}

// ---------------- count tokens per expert ----------------
__global__ __launch_bounds__(256) void count_kernel(
    const int2* __restrict__ experts, int* __restrict__ counts, int T) {
  __shared__ int lc[NE];
  if (threadIdx.x < NE) lc[threadIdx.x] = 0;
  __syncthreads();
  const int t = blockIdx.x * 256 + threadIdx.x;
  if (t < T) {
    int2 e = experts[t];
    atomicAdd(&lc[e.x], 1);
    atomicAdd(&lc[e.y], 1);
  }
  __syncthreads();
  if (threadIdx.x < NE && lc[threadIdx.x] > 0)
    atomicAdd(&counts[threadIdx.x], lc[threadIdx.x]);
}

__global__ void offsets_kernel(const int* __restrict__ counts, int* __restrict__ offsets) {
  int s = 0;
  for (int e = 0; e < NE; e++) { offsets[e] = s; s += counts[e]; }
}

// ---------------- scatter: compact expert groups + inverse map (slots per token) ----------------
__global__ __launch_bounds__(256) void scatter_kernel(
    const int2* __restrict__ experts, const int* __restrict__ offsets,
    int* __restrict__ cursors, int* __restrict__ tok_id,
    int2* __restrict__ slots, int T) {
  __shared__ int lc[NE], lb[NE];
  if (threadIdx.x < NE) lc[threadIdx.x] = 0;
  __syncthreads();
  const int t = blockIdx.x * 256 + threadIdx.x;
  int2 e = make_int2(0, 0);
  int p0 = 0, p1 = 0;
  if (t < T) {
    e = experts[t];
    p0 = atomicAdd(&lc[e.x], 1);
    p1 = atomicAdd(&lc[e.y], 1);
  }
  __syncthreads();
  if (threadIdx.x < NE) lb[threadIdx.x] = atomicAdd(&cursors[threadIdx.x], lc[threadIdx.x]);
  __syncthreads();
  if (t < T) {
    const int s0 = offsets[e.x] + lb[e.x] + p0;
    const int s1 = offsets[e.y] + lb[e.y] + p1;
    tok_id[s0] = t;
    tok_id[s1] = t;
    slots[t] = make_int2(s0, s1);
  }
}

// ---------------- weight transpose + fp32->bf16 convert ----------------
// Wgu: [e][nc][k], nc = ((n>>3)<<4) | (which<<3) | (n&7); Wd: [e][n][k]
__global__ __launch_bounds__(256) void convert_kernel(
    const float* __restrict__ wg, const float* __restrict__ wu,
    const float* __restrict__ wd, u16* __restrict__ Wgu, u16* __restrict__ Wd) {
  const int z = blockIdx.z;        // mat*8 + e
  const int mat = z >> 3;
  const int e = z & 7;
  const float* src = (mat == 0 ? wg : (mat == 1 ? wu : wd)) + (size_t)e * DD * DD;
  __shared__ float tile[64][65];
  const int k0 = blockIdx.y * 64, n0 = blockIdx.x * 64;
  const int tx = threadIdx.x & 63, ty = threadIdx.x >> 6;
#pragma unroll
  for (int i = 0; i < 16; i++) {
    const int kk = i * 4 + ty;
    tile[kk][tx] = src[(size_t)(k0 + kk) * DD + n0 + tx];
  }
  __syncthreads();
#pragma unroll
  for (int i = 0; i < 16; i++) {
    const int nn = i * 4 + ty;
    const int n = n0 + nn;
    const u16 h = f2bf(tile[tx][nn]);   // = src[k0+tx][n]
    if (mat == 2) {
      Wd[((size_t)e * DD + n) * DD + k0 + tx] = h;
    } else {
      const int nc = ((n >> 3) << 4) | (mat << 3) | (n & 7);
      Wgu[((size_t)e * 2048 + nc) * DD + k0 + tx] = h;
    }
  }
}

// ======================================================================
// 128x128-tile grouped GEMM engine (round-0/round-5 verified data path),
// K-loop with T4 counted-vmcnt so the prefetch SPANS iterations:
//   prologue: STAGE(buf0, k=0)                  // 8 loads in flight
//   iter kk<15: STAGE(buf^1, kk+1)              // +8 -> 16 in flight
//               vmcnt(8)                        // retire ONLY prev stage
//               barrier                         // all waves: buf data landed
//               16 ds_read_b128(buf); lgkmcnt(0); 32 MFMA (setprio)
//               barrier                         // readers done; overwrite safe
//   iter 15:    vmcnt(0); barrier; reads; MFMA  // drain (no new stage)
// vmcnt(0) never appears in the steady-state loop (T4, m218).
// ======================================================================

#define STAGE(BUF, KOFF)                                                \
  {                                                                     \
    _Pragma("unroll")                                                   \
    for (int i = 0; i < 4; i++) {                                       \
      GLOAD_LDS16(srcA[i] + (KOFF), &As[(BUF) * 8192 + t * 8 + i * 2048]); \
      GLOAD_LDS16(srcB[i] + (KOFF), &Bs[(BUF) * 8192 + t * 8 + i * 2048]); \
    }                                                                   \
  }

#define KSTEP(VM)                                                       \
  {                                                                     \
    __builtin_amdgcn_sched_barrier(0);                                  \
    asm volatile("s_waitcnt vmcnt(" VM ")");                            \
    __builtin_amdgcn_s_barrier();                                       \
    __builtin_amdgcn_sched_barrier(0);                                  \
    short8 a0[4], b0[4], a1[4], b1[4];                                  \
    const u32 base_ = (u32)cur * 16384u;                                \
    const u32 a0_ = asb + base_ + offA + cks0;                          \
    const u32 b0_ = bsb + base_ + offB + cks0;                          \
    const u32 a1_ = asb + base_ + offA + cks1;                          \
    const u32 b1_ = bsb + base_ + offB + cks1;                          \
    DSR(a0[0], a0_, "0");    DSR(a0[1], a0_, "2048");                   \
    DSR(a0[2], a0_, "4096"); DSR(a0[3], a0_, "6144");                   \
    DSR(b0[0], b0_, "0");    DSR(b0[1], b0_, "2048");                   \
    DSR(b0[2], b0_, "4096"); DSR(b0[3], b0_, "6144");                   \
    DSR(a1[0], a1_, "0");    DSR(a1[1], a1_, "2048");                   \
    DSR(a1[2], a1_, "4096"); DSR(a1[3], a1_, "6144");                   \
    DSR(b1[0], b1_, "0");    DSR(b1[1], b1_, "2048");                   \
    DSR(b1[2], b1_, "4096"); DSR(b1[3], b1_, "6144");                   \
    asm volatile("s_waitcnt lgkmcnt(0)");                               \
    __builtin_amdgcn_sched_barrier(0);                                  \
    __builtin_amdgcn_s_setprio(1);                                      \
    _Pragma("unroll")                                                   \
    for (int i = 0; i < 4; i++)                                         \
      _Pragma("unroll")                                                 \
      for (int j = 0; j < 4; j++)                                       \
        acc[i][j] = __builtin_amdgcn_mfma_f32_16x16x32_bf16(            \
            a0[i], b0[j], acc[i][j], 0, 0, 0);                          \
    _Pragma("unroll")                                                   \
    for (int i = 0; i < 4; i++)                                         \
      _Pragma("unroll")                                                 \
      for (int j = 0; j < 4; j++)                                       \
        acc[i][j] = __builtin_amdgcn_mfma_f32_16x16x32_bf16(            \
            a1[i], b1[j], acc[i][j], 0, 0, 0);                          \
    __builtin_amdgcn_s_setprio(0);                                      \
    __builtin_amdgcn_sched_barrier(0);                                  \
    __builtin_amdgcn_s_barrier();                                       \
    __builtin_amdgcn_sched_barrier(0);                                  \
  }

#define GEMM128_LOOP()                                                  \
  STAGE(0, 0);                                                          \
  int cur = 0;                                                          \
  _Pragma("unroll 1")                                                   \
  for (int kk = 0; kk < 15; ++kk) {                                     \
    STAGE(cur ^ 1, (kk + 1) * 64);                                      \
    KSTEP("8");                                                         \
    cur ^= 1;                                                           \
  }                                                                     \
  KSTEP("0");

// ---------------- grouped GEMM 1: H = silu(x@Wg)*(x@Wu) ----------------
__global__ __launch_bounds__(256, 2) void gateup_kernel(
    const u16* __restrict__ xbf, const u16* __restrict__ Wgu,
    const int* __restrict__ tok_id, const int* __restrict__ offsets,
    const int* __restrict__ counts, u16* __restrict__ H) {
  const int e = blockIdx.z;
  const int cnt = counts[e];
  const int m0 = blockIdx.y * 128;
  if (m0 >= cnt) return;
  const int off = offsets[e];
  const int n0 = blockIdx.x * 128;

  __shared__ u16 As[2 * 8192];   // 2 bufs x [128 rows][64 k] = 32 KB
  __shared__ u16 Bs[2 * 8192];   // 32 KB

  const int t = threadIdx.x;
  const int lane = t & 63;
  const int wave = t >> 6;
  const int wm = (wave >> 1) * 64;
  const int wn = (wave & 1) * 64;
  const int r16 = lane & 15;
  const int quad = lane >> 4;
  const u32 offA = (u32)((wm + r16) * 128);     // byte offset of row base
  const u32 offB = (u32)((wn + r16) * 128);
  const u32 cks0 = (u32)(((quad) ^ (r16 & 7)) * 16);
  const u32 cks1 = (u32)(((4 + quad) ^ (r16 & 7)) * 16);
  const u32 asb = LDSA(&As[0]);
  const u32 bsb = LDSA(&Bs[0]);

  // DMA mapping (round-0 verified): issue i covers rows i*32 + (t>>3); lane supplies
  // chunk position t&7, whose LOGICAL k-chunk is (t&7) ^ (row&7) (XOR swizzle).
  const int drow = t >> 3;
  const int dpos = t & 7;
  const u16* srcA[4];
  const u16* srcB[4];
  const u16* bbase = Wgu + ((size_t)e * 2048 + n0) * DD;
#pragma unroll
  for (int i = 0; i < 4; i++) {
    const int row = drow + i * 32;
    int r = m0 + row; if (r > cnt - 1) r = cnt - 1;
    const int tok = tok_id[off + r];
    const int ka = (dpos ^ (row & 7)) * 8;
    srcA[i] = xbf + (size_t)tok * DD + ka;
    srcB[i] = bbase + (size_t)row * DD + ka;
  }

  floatx4 acc[4][4];
#pragma unroll
  for (int i = 0; i < 4; i++)
#pragma unroll
    for (int j = 0; j < 4; j++)
      acc[i][j] = (floatx4){0.f, 0.f, 0.f, 0.f};

  GEMM128_LOOP();

  // epilogue: pair gate (bit3=0) with up (bit3=1) via shfl_xor 8, silu, write bf16 H
#pragma unroll
  for (int i = 0; i < 4; i++) {
    const int mb = m0 + wm + i * 16 + quad * 4;
#pragma unroll
    for (int j = 0; j < 4; j++) {
      const int nc = n0 + wn + j * 16 + r16;
      const int ng = ((nc >> 4) << 3) | (nc & 7);
#pragma unroll
      for (int r = 0; r < 4; r++) {
        const float v = acc[i][j][r];
        const float pv = __shfl_xor(v, 8);
        const float g = (lane & 8) ? pv : v;
        const float u = (lane & 8) ? v : pv;
        const float hv = g * u / (1.f + __expf(-g));
        const int m = mb + r;
        if (!(lane & 8) && m < cnt)
          H[(size_t)(off + m) * DD + ng] = f2bf(hv);
      }
    }
  }
}

// ---------------- grouped GEMM 2: Y[slot] = H[slot] @ Wd  (bf16 stores, no atomics) ----------------
__global__ __launch_bounds__(256, 2) void down_kernel(
    const u16* __restrict__ H, const u16* __restrict__ Wd,
    const int* __restrict__ counts, const int* __restrict__ offsets,
    u16* __restrict__ Y, int TK2) {
  const int e = blockIdx.z;
  const int cnt = counts[e];
  const int m0 = blockIdx.y * 128;
  if (m0 >= cnt) return;
  const int off = offsets[e];
  const int n0 = blockIdx.x * 128;

  __shared__ u16 As[2 * 8192];
  __shared__ u16 Bs[2 * 8192];

  const int t = threadIdx.x;
  const int lane = t & 63;
  const int wave = t >> 6;
  const int wm = (wave >> 1) * 64;
  const int wn = (wave & 1) * 64;
  const int r16 = lane & 15;
  const int quad = lane >> 4;
  const u32 offA = (u32)((wm + r16) * 128);
  const u32 offB = (u32)((wn + r16) * 128);
  const u32 cks0 = (u32)(((quad) ^ (r16 & 7)) * 16);
  const u32 cks1 = (u32)(((4 + quad) ^ (r16 & 7)) * 16);
  const u32 asb = LDSA(&As[0]);
  const u32 bsb = LDSA(&Bs[0]);

  const int drow = t >> 3;
  const int dpos = t & 7;
  const u16* srcA[4];
  const u16* srcB[4];
  const u16* bbase = Wd + ((size_t)e * DD + n0) * DD;
#pragma unroll
  for (int i = 0; i < 4; i++) {
    const int row = drow + i * 32;
    int r = off + m0 + row; if (r > TK2 - 1) r = TK2 - 1;
    const int ka = (dpos ^ (row & 7)) * 8;
    srcA[i] = H + (size_t)r * DD + ka;
    srcB[i] = bbase + (size_t)row * DD + ka;
  }

  floatx4 acc[4][4];
#pragma unroll
  for (int i = 0; i < 4; i++)
#pragma unroll
    for (int j = 0; j < 4; j++)
      acc[i][j] = (floatx4){0.f, 0.f, 0.f, 0.f};

  GEMM128_LOOP();

#pragma unroll
  for (int i = 0; i < 4; i++) {
    const int mb = m0 + wm + i * 16 + quad * 4;
#pragma unroll
    for (int r = 0; r < 4; r++) {
      const int m = mb + r;
      if (m < cnt) {
        u16* yrow = Y + (size_t)(off + m) * DD + n0 + wn + r16;
#pragma unroll
        for (int j = 0; j < 4; j++)
          yrow[j * 16] = f2bf(acc[i][j][r]);
      }
    }
  }
}

#undef STAGE
#undef KSTEP

// ---------------- combine: out[t] = w0*Y[s0] + w1*Y[s1] ----------------
__global__ __launch_bounds__(256) void combine_kernel(
    const u16* __restrict__ Y, const int2* __restrict__ slots,
    const float2* __restrict__ wts, float* __restrict__ out, int T) {
  const int wave = threadIdx.x >> 6;
  const int lane = threadIdx.x & 63;
  const int t = blockIdx.x * 4 + wave;
  if (t >= T) return;
  const int2 s = slots[t];
  const float2 w = wts[t];
  const uint4* y0 = (const uint4*)(Y + (size_t)s.x * DD);
  const uint4* y1 = (const uint4*)(Y + (size_t)s.y * DD);
  float4* o = (float4*)(out + (size_t)t * DD);
#pragma unroll
  for (int c = 0; c < 2; c++) {
    const int idx = lane + c * 64;          // 128 uint4 per row (8 bf16 each)
    const uint4 a = y0[idx];
    const uint4 b = y1[idx];
    const u32 au[4] = {a.x, a.y, a.z, a.w};
    const u32 bu[4] = {b.x, b.y, b.z, b.w};
    float4 r[2];
#pragma unroll
    for (int q = 0; q < 4; q++) {
      const float2 fa = bf2f2(au[q]);
      const float2 fb = bf2f2(bu[q]);
      ((float*)r)[q * 2]     = w.x * fa.x + w.y * fb.x;
      ((float*)r)[q * 2 + 1] = w.x * fa.y + w.y * fb.y;
    }
    o[idx * 2]     = r[0];
    o[idx * 2 + 1] = r[1];
  }
}

extern "C" void kernel_launch(void* const* d_in, const int* in_sizes, int n_in,
                              void* d_out, int out_size, void* d_ws, size_t ws_size,
                              hipStream_t stream) {
  const float* x  = (const float*)d_in[0];
  const float* rw = (const float*)d_in[1];
  const float* rb = (const float*)d_in[2];
  const float* wg = (const float*)d_in[3];
  const float* wu = (const float*)d_in[4];
  const float* wd = (const float*)d_in[5];
  float* out = (float*)d_out;
  const int T = in_sizes[0] / DD;       // 16384
  const int TK2 = 2 * T;

  // workspace carve. Y (64MB) aliases [Wgu(32MB) xbf(32MB)], which are dead after gateup.
  char* p = (char*)d_ws;
  int* ctrl = (int*)p; p += 256;        // [0..7]=counts [8..15]=cursors [16..23]=offsets
  int2* experts = (int2*)p;  p += (size_t)T * 8;
  float2* wtsp  = (float2*)p; p += (size_t)T * 8;
  int* tok_id   = (int*)p;   p += (size_t)TK2 * 4;
  int2* slots   = (int2*)p;  p += (size_t)T * 8;
  u16* Wd       = (u16*)p;   p += (size_t)NE * DD * DD * 2;
  u16* H        = (u16*)p;   p += (size_t)TK2 * DD * 2;
  u16* Wgu      = (u16*)p;   // 32 MB
  u16* xbf      = (u16*)(p + (size_t)NE * 2048 * DD * 2);  // 32 MB
  u16* Y        = (u16*)p;   // 64 MB, aliases Wgu+xbf
  p += (size_t)TK2 * DD * 2;
  if ((size_t)(p - (char*)d_ws) > ws_size) return;  // insufficient scratch -> visible failure

  hipMemsetAsync(ctrl, 0, 256, stream);

  router_kernel<<<T / 4, 256, 0, stream>>>(x, rw, rb, experts, wtsp, xbf, T);
  count_kernel<<<T / 256, 256, 0, stream>>>(experts, ctrl, T);
  offsets_kernel<<<1, 1, 0, stream>>>(ctrl, ctrl + 16);
  scatter_kernel<<<T / 256, 256, 0, stream>>>(experts, ctrl + 16, ctrl + 8, tok_id, slots, T);
  convert_kernel<<<dim3(16, 16, 24), 256, 0, stream>>>(wg, wu, wd, Wgu, Wd);
  gateup_kernel<<<dim3(16, (T + 127) / 128, NE), 256, 0, stream>>>(
      xbf, Wgu, tok_id, ctrl + 16, ctrl, H);
  down_kernel<<<dim3(8, (T + 127) / 128, NE), 256, 0, stream>>>(
      H, Wd, ctrl, ctrl + 16, Y, TK2);
  combine_kernel<<<T / 4, 256, 0, stream>>>(Y, slots, wtsp, out, T);
}